// Round 22
// baseline (210.730 us; speedup 1.0000x reference)
//
#include <hip/hip_runtime.h>

#define BB  8
#define NN1 1024
#define NN2 256
#define DD  16
#define EE  16
#define NCOL (NN2 * DD)   // 4096
#define SLPB 2            // slices per k_pm block

using bf16x8  = __attribute__((ext_vector_type(8))) short;
using f32x4   = __attribute__((ext_vector_type(4))) float;
using ushort8 = __attribute__((ext_vector_type(8))) unsigned short;

__device__ __forceinline__ ushort f2bf(float x) {
  unsigned u = __float_as_uint(x);
  unsigned r = (u + 0x7FFFu + ((u >> 16) & 1u)) >> 16;
  return (ushort)r;
}
__device__ __forceinline__ float bf2f(ushort u) {
  return __uint_as_float((unsigned)u << 16);
}
__device__ __forceinline__ unsigned pkbf(float a, float b) {
  return (unsigned)f2bf(a) | ((unsigned)f2bf(b) << 16);
}

#define GLDS16(g, l)                                                       \
  __builtin_amdgcn_global_load_lds(                                        \
      (const __attribute__((address_space(1))) void*)(g),                  \
      (__attribute__((address_space(3))) void*)(l), 16, 0, 0)

// ---------------------------------------------------------------------------
// k_prep: transpose + fp32->bf16 + swizzle.
//  ps=0: 16B-chunk XOR within 64B blocks, chunk g <- g ^ ((row>>1)&3)
//  ps=1: full 3-bit chunk XOR within 128B blocks: chunk g <- g ^ (row&7)
// src fp32 [kd(k)][nr], dst bf16 [nr][kd].
// ---------------------------------------------------------------------------
__global__ __launch_bounds__(256)
void k_prep(const float* __restrict__ src, ushort* __restrict__ dst,
            int nr, int kd, size_t srcBatch, size_t dstBatch, int ps) {
  __shared__ float tile[64][65];
  const int t = threadIdx.x;
  const int r0 = blockIdx.x * 64;
  const int k0 = blockIdx.y * 64;
  const float* s = src + (size_t)blockIdx.z * srcBatch;
  ushort* d = dst + (size_t)blockIdx.z * dstBatch;

#pragma unroll
  for (int it = 0; it < 4; ++it) {
    const int kr = it * 16 + (t >> 4);
    const int rc = (t & 15) * 4;
    float4 v = *reinterpret_cast<const float4*>(&s[(size_t)(k0 + kr) * nr + r0 + rc]);
    tile[kr][rc] = v.x; tile[kr][rc + 1] = v.y;
    tile[kr][rc + 2] = v.z; tile[kr][rc + 3] = v.w;
  }
  __syncthreads();

#pragma unroll
  for (int pass = 0; pass < 2; ++pass) {
    const int task = t + pass * 256;
    const int pr = task >> 3;
    const int gl = task & 7;
    const int r = r0 + pr;
    int klb;
    if (ps) {
      klb = (gl ^ (r & 7)) * 8;
    } else {
      const int f = (r >> 1) & 3;
      klb = (gl >> 2) * 32 + ((gl & 3) ^ f) * 8;
    }
    unsigned w[4];
#pragma unroll
    for (int e2 = 0; e2 < 4; ++e2)
      w[e2] = pkbf(tile[klb + e2 * 2][pr], tile[klb + e2 * 2 + 1][pr]);
    *reinterpret_cast<uint4*>(&d[(size_t)r * kd + k0 + gl * 8]) =
        *reinterpret_cast<const uint4*>(w);
  }
}

// ---------------------------------------------------------------------------
// k_mode0_mfma: y[b][p][c] = sum_k adj0[k][p] * X[b][k][c] -> bf16
// R15 8-phase loop (unchanged). R22: epilogue LDS-bounce -- acc -> SH bf16
// tile (pitch 256, 16B-chunk XOR (row&7)) -> 8x global_store_dwordx4/thread
// (replaces 64 scalar b16 stores). SH unions As/Bs (same 128 KB).
// ---------------------------------------------------------------------------
__global__ __launch_bounds__(1024)
void k_mode0_mfma(const ushort* __restrict__ At, const ushort* __restrict__ Xt,
                  ushort* __restrict__ Y) {
  __shared__ ushort SH[65536];     // 128 KB: loop: As[2]|Bs[2]; epi: C tile
  ushort* As = SH;                 // [buf*16384 + idx]
  ushort* Bs = SH + 32768;

  const int t = threadIdx.x;
  const int lane = t & 63;
  const int wid = t >> 6;
  const int wr = wid >> 2;
  const int wc = wid & 3;

  const int nwg = (int)gridDim.x;
  const int wg  = (int)blockIdx.x;
  const int orig = (wg & 7) * (nwg >> 3) + (wg >> 3);
  const int b  = orig >> 6;
  const int rem = orig & 63;
  const int c0 = (rem >> 2) << 8;
  const int p0 = (rem & 3) << 8;

  const ushort* Bb = Xt + (size_t)b * (NCOL * 1024);

  f32x4 acc[4][4];
#pragma unroll
  for (int i = 0; i < 4; ++i)
#pragma unroll
    for (int j = 0; j < 4; ++j) acc[i][j] = (f32x4)0.f;

  const int lm = lane & 15, g = lane >> 4;

  const int ksx0 = (g ^ (lm & 7)) << 3;
  const int ksx1 = ksx0 ^ 32;
  int aoff[4], boff[4];
#pragma unroll
  for (int f = 0; f < 4; ++f) {
    aoff[f] = (wr * 64 + f * 16 + lm) * 64;
    boff[f] = (wc * 64 + f * 16 + lm) * 64;
  }

#define STG_A(buf, kt, h) do {                                             \
    const int rs_ = ((wid >> 2) << 6) + (h) * 32 + ((wid & 3) << 3);       \
    GLDS16(At + (size_t)(p0 + rs_ + (lane >> 3)) * 1024 + (kt) * 64 +      \
               (lane & 7) * 8, &As[(buf) * 16384 + rs_ * 64]);             \
  } while (0)

#define STG_B(buf, kt, h) do {                                             \
    const int rs_ = ((wid >> 2) << 6) + (h) * 32 + ((wid & 3) << 3);       \
    GLDS16(Bb + (size_t)(c0 + rs_ + (lane >> 3)) * 1024 + (kt) * 64 +      \
               (lane & 7) * 8, &Bs[(buf) * 16384 + rs_ * 64]);             \
  } while (0)

#define VM3 asm volatile("s_waitcnt vmcnt(3)" ::: "memory")
#define VM2 asm volatile("s_waitcnt vmcnt(2)" ::: "memory")
#define VM1 asm volatile("s_waitcnt vmcnt(1)" ::: "memory")
#define VM0 asm volatile("s_waitcnt vmcnt(0)" ::: "memory")
#define NOWAIT ((void)0)
#define NOSTG  ((void)0)

#define PHASE(buf, qi, qj, STGSTMT, WAITSTMT) do {                         \
    STGSTMT;                                                               \
    WAITSTMT;                                                              \
    __builtin_amdgcn_s_barrier();                                          \
    __builtin_amdgcn_sched_barrier(0);                                     \
    bf16x8 a00 = *reinterpret_cast<const bf16x8*>(&As[(buf)*16384 + aoff[(qi)*2+0] + ksx0]); \
    bf16x8 a10 = *reinterpret_cast<const bf16x8*>(&As[(buf)*16384 + aoff[(qi)*2+1] + ksx0]); \
    bf16x8 b00 = *reinterpret_cast<const bf16x8*>(&Bs[(buf)*16384 + boff[(qj)*2+0] + ksx0]); \
    bf16x8 b10 = *reinterpret_cast<const bf16x8*>(&Bs[(buf)*16384 + boff[(qj)*2+1] + ksx0]); \
    bf16x8 a01 = *reinterpret_cast<const bf16x8*>(&As[(buf)*16384 + aoff[(qi)*2+0] + ksx1]); \
    bf16x8 a11 = *reinterpret_cast<const bf16x8*>(&As[(buf)*16384 + aoff[(qi)*2+1] + ksx1]); \
    bf16x8 b01 = *reinterpret_cast<const bf16x8*>(&Bs[(buf)*16384 + boff[(qj)*2+0] + ksx1]); \
    bf16x8 b11 = *reinterpret_cast<const bf16x8*>(&Bs[(buf)*16384 + boff[(qj)*2+1] + ksx1]); \
    __builtin_amdgcn_s_setprio(1);                                         \
    acc[(qi)*2+0][(qj)*2+0] = __builtin_amdgcn_mfma_f32_16x16x32_bf16(a00, b00, acc[(qi)*2+0][(qj)*2+0], 0, 0, 0); \
    acc[(qi)*2+0][(qj)*2+1] = __builtin_amdgcn_mfma_f32_16x16x32_bf16(a00, b10, acc[(qi)*2+0][(qj)*2+1], 0, 0, 0); \
    acc[(qi)*2+1][(qj)*2+0] = __builtin_amdgcn_mfma_f32_16x16x32_bf16(a10, b00, acc[(qi)*2+1][(qj)*2+0], 0, 0, 0); \
    acc[(qi)*2+1][(qj)*2+1] = __builtin_amdgcn_mfma_f32_16x16x32_bf16(a10, b10, acc[(qi)*2+1][(qj)*2+1], 0, 0, 0); \
    acc[(qi)*2+0][(qj)*2+0] = __builtin_amdgcn_mfma_f32_16x16x32_bf16(a01, b01, acc[(qi)*2+0][(qj)*2+0], 0, 0, 0); \
    acc[(qi)*2+0][(qj)*2+1] = __builtin_amdgcn_mfma_f32_16x16x32_bf16(a01, b11, acc[(qi)*2+0][(qj)*2+1], 0, 0, 0); \
    acc[(qi)*2+1][(qj)*2+0] = __builtin_amdgcn_mfma_f32_16x16x32_bf16(a11, b01, acc[(qi)*2+1][(qj)*2+0], 0, 0, 0); \
    acc[(qi)*2+1][(qj)*2+1] = __builtin_amdgcn_mfma_f32_16x16x32_bf16(a11, b11, acc[(qi)*2+1][(qj)*2+1], 0, 0, 0); \
    __builtin_amdgcn_s_setprio(0);                                         \
  } while (0)

  STG_A(0, 0, 0); STG_B(0, 0, 0); STG_A(0, 0, 1); STG_B(0, 0, 1);

  for (int it = 0; it < 8; ++it) {
    const int t1 = 2 * it + 1, t2 = 2 * it + 2;
    PHASE(0, 0, 0, STG_A(1, t1, 0), VM3);
    PHASE(0, 1, 0, STG_B(1, t1, 0), VM3);
    PHASE(0, 0, 1, STG_A(1, t1, 1), VM3);
    PHASE(0, 1, 1, STG_B(1, t1, 1), NOWAIT);
    __builtin_amdgcn_s_barrier();
    if (it < 7) {
      PHASE(1, 0, 0, STG_A(0, t2, 0), VM3);
      PHASE(1, 1, 0, STG_B(0, t2, 0), VM3);
      PHASE(1, 0, 1, STG_A(0, t2, 1), VM3);
      PHASE(1, 1, 1, STG_B(0, t2, 1), NOWAIT);
    } else {
      PHASE(1, 0, 0, NOSTG, VM2);
      PHASE(1, 1, 0, NOSTG, VM1);
      PHASE(1, 0, 1, NOSTG, VM0);
      PHASE(1, 1, 1, NOSTG, NOWAIT);
    }
    __builtin_amdgcn_s_barrier();
  }
#undef PHASE
#undef STG_A
#undef STG_B

  // ---- epilogue: acc -> SH bf16 tile (XOR-swizzled) -> vectorized store ----
  const int orow = g * 4;
#pragma unroll
  for (int i = 0; i < 4; ++i)
#pragma unroll
    for (int j = 0; j < 4; ++j)
#pragma unroll
      for (int e = 0; e < 4; ++e) {
        const int row = wr * 64 + i * 16 + orow + e;
        const int col = wc * 64 + j * 16 + lm;
        SH[(row * 256 + col) ^ ((row & 7) << 3)] = f2bf(acc[i][j][e]);
      }
  __syncthreads();

  {
    ushort* Yb = Y + (size_t)b * ((size_t)NN1 * NCOL);
    const int r  = t >> 2;            // tile row 0..255
    const int cb = (t & 3) * 64;      // 64-ushort col run
    const int sw = r & 7;
    const int base = r * 256 + cb;
    ushort* gdst = Yb + (size_t)(p0 + r) * NCOL + c0 + cb;
#pragma unroll
    for (int uL = 0; uL < 8; ++uL) {
      const uint4 v = *reinterpret_cast<const uint4*>(&SH[base + ((uL ^ sw) << 3)]);
      *reinterpret_cast<uint4*>(gdst + (uL << 3)) = v;
    }
  }
}

// ---------------------------------------------------------------------------
// k_pm: fused projection(MFMA) + mode1 per SLPB slices (512 thr).
// R16-exact (best measured): xy pitch-40 staging, proj MFMAs with r in acc,
// s -> St (mode1c Bs layout), phase-2 BK=64 double-buffered A1t (ps=1 swz),
// LDS 80 KB (As dbuf aliases xy region).
// ---------------------------------------------------------------------------
__global__ __launch_bounds__(512)
void k_pm(const float* __restrict__ x, const ushort* __restrict__ y0,
          const ushort* __restrict__ A1t,
          const float* __restrict__ W,   const float* __restrict__ bW,
          const float* __restrict__ W0,  const float* __restrict__ b0,
          const float* __restrict__ W1,  const float* __restrict__ b1,
          const float* __restrict__ W01, const float* __restrict__ b01,
          float* __restrict__ out) {
  __shared__ ushort SH[40960];       // 80 KB
  ushort* xy  = SH;                  // phase 1: 512 rows x 40 (x|y|pad)
  ushort* Asb = SH;                  // phase 2: 2 bufs x 16384 (256 q x 64 k)
  ushort* Stp = SH + 32768;          // 8 kc x 32 m x 32 j  (16 KB)

  const int t = threadIdx.x;
  const int lane = t & 63;
  const int wid = t >> 6;            // 0..7
  const int lm = lane & 15, g = lane >> 4;
  const int wq  = wid >> 1;          // 0..3 : 64-q stripe
  const int wmi = wid & 1;           // 0..1 : slice
  const size_t sl0 = (size_t)blockIdx.x * SLPB;

  // ---- phase 1a: stage x (convert) and y0 rows into xy (pitch 40) ----
  {
    const size_t base = (sl0 * NCOL) + (size_t)t * DD;   // row j_global = t
    const float4 x0 = *reinterpret_cast<const float4*>(&x[base]);
    const float4 x1 = *reinterpret_cast<const float4*>(&x[base + 4]);
    const float4 x2 = *reinterpret_cast<const float4*>(&x[base + 8]);
    const float4 x3 = *reinterpret_cast<const float4*>(&x[base + 12]);
    const uint4 yv0 = *reinterpret_cast<const uint4*>(&y0[base]);
    const uint4 yv1 = *reinterpret_cast<const uint4*>(&y0[base + 8]);
    unsigned xw0[4] = {pkbf(x0.x, x0.y), pkbf(x0.z, x0.w), pkbf(x1.x, x1.y), pkbf(x1.z, x1.w)};
    unsigned xw1[4] = {pkbf(x2.x, x2.y), pkbf(x2.z, x2.w), pkbf(x3.x, x3.y), pkbf(x3.z, x3.w)};
    ushort* row = xy + t * 40;
    *reinterpret_cast<uint4*>(row)      = *reinterpret_cast<const uint4*>(xw0);
    *reinterpret_cast<uint4*>(row + 8)  = *reinterpret_cast<const uint4*>(xw1);
    *reinterpret_cast<uint4*>(row + 16) = yv0;
    *reinterpret_cast<uint4*>(row + 24) = yv1;
  }

  // ---- W fragments + bias (k = g*8+jj over [x(16)|y0(16)]) ----
  bf16x8 wfr, wfs;
#pragma unroll
  for (int jj = 0; jj < 8; ++jj) {
    const int k = g * 8 + jj;
    const float vr = (k < 16) ? W[k * 16 + lm]  : W0[(k - 16) * 16 + lm];
    const float vs = (k < 16) ? W1[k * 16 + lm] : W01[(k - 16) * 16 + lm];
    wfr[jj] = (short)f2bf(vr);
    wfs[jj] = (short)f2bf(vs);
  }
  const float bias = bW[lm] + b0[lm] + b1[lm] + b01[lm];

  __syncthreads();

  // ---- phase 1b: projection MFMAs; r accumulates in acc, s -> St ----
  f32x4 acc[4];
#pragma unroll
  for (int i = 0; i < 4; ++i) {
    const int grp = wmi * 16 + wq * 4 + i;
    const int row = grp * 16 + lm;
    const bf16x8 a = *reinterpret_cast<const bf16x8*>(&xy[row * 40 + g * 8]);

    f32x4 cb; cb[0] = bias; cb[1] = bias; cb[2] = bias; cb[3] = bias;
    acc[i] = __builtin_amdgcn_mfma_f32_16x16x32_bf16(a, wfr, cb, 0, 0, 0);
    const f32x4 sD = __builtin_amdgcn_mfma_f32_16x16x32_bf16(a, wfs, (f32x4)0.f, 0, 0, 0);

    const int m = wmi * 16 + lm;
    const int kc = wq * 2 + (i >> 1);
    const int chunkL = ((i & 1) << 1) + (g >> 1);
    const int phys = chunkL ^ ((m >> 1) & 3);
    unsigned pw[2] = {pkbf(sD[0], sD[1]), pkbf(sD[2], sD[3])};
    *reinterpret_cast<uint2*>(&Stp[kc * 1024 + m * 32 + phys * 8 + (g & 1) * 4]) =
        *reinterpret_cast<const uint2*>(pw);
  }

  __syncthreads();   // St complete; all xy reads done -> Asb region free

  // ---- phase 2: mode1 GEMM, BK=64 (4 iters x 8 MFMAs) ----
#define STAGEA(buf, kt)                                                    \
  do {                                                                     \
    _Pragma("unroll")                                                      \
    for (int is = 0; is < 4; ++is) {                                       \
      const int rowbase = wid * 32 + is * 8;                               \
      GLDS16(A1t + (size_t)(rowbase + (lane >> 3)) * 256 + (kt) * 64 +     \
                 (lane & 7) * 8,                                           \
             Asb + (buf) * 16384 + rowbase * 64);                          \
    }                                                                      \
  } while (0)

  int aro[4][2];
#pragma unroll
  for (int f = 0; f < 4; ++f) {
    const int ra = wq * 64 + f * 16 + lm;
#pragma unroll
    for (int ks = 0; ks < 2; ++ks)
      aro[f][ks] = ra * 64 + (((ks * 4 + g) ^ (ra & 7)) << 3);
  }
  const int rwB = wmi * 16 + lm;
  const int bofs = (rwB * 32) + ((g ^ ((rwB >> 1) & 3)) << 3);

  STAGEA(0, 0);
  int cur = 0;
  for (int kt = 0; kt < 4; ++kt) {
    if (kt < 3) {
      STAGEA(cur ^ 1, kt + 1);
      asm volatile("s_waitcnt vmcnt(4)" ::: "memory");
    } else {
      asm volatile("s_waitcnt vmcnt(0)" ::: "memory");
    }
    __builtin_amdgcn_s_barrier();
    __builtin_amdgcn_sched_barrier(0);

#pragma unroll
    for (int ks = 0; ks < 2; ++ks) {
      const int kc = kt * 2 + ks;
      bf16x8 af[4];
#pragma unroll
      for (int f = 0; f < 4; ++f)
        af[f] = *reinterpret_cast<const bf16x8*>(&Asb[cur * 16384 + aro[f][ks]]);
      const bf16x8 bfr = *reinterpret_cast<const bf16x8*>(&Stp[kc * 1024 + bofs]);
      __builtin_amdgcn_s_setprio(1);
#pragma unroll
      for (int i = 0; i < 4; ++i)
        acc[i] = __builtin_amdgcn_mfma_f32_16x16x32_bf16(af[i], bfr, acc[i], 0, 0, 0);
      __builtin_amdgcn_s_setprio(0);
    }

    __builtin_amdgcn_sched_barrier(0);
    __builtin_amdgcn_s_barrier();
    cur ^= 1;
  }
#undef STAGEA

  // ---- epilogue: out = relu(acc), single fp32 write ----
  float* os = out + (sl0 + wmi) * NCOL;
#pragma unroll
  for (int i = 0; i < 4; ++i) {
    const int qb = wq * 64 + i * 16 + g * 4;
#pragma unroll
    for (int rr = 0; rr < 4; ++rr)
      os[(size_t)(qb + rr) * EE + lm] = fmaxf(acc[i][rr], 0.f);
  }
}

// ---------------------------------------------------------------------------
extern "C" void kernel_launch(void* const* d_in, const int* in_sizes, int n_in,
                              void* d_out, int out_size, void* d_ws, size_t ws_size,
                              hipStream_t stream) {
  const float* x    = (const float*)d_in[0];
  const float* adj0 = (const float*)d_in[1];
  const float* adj1 = (const float*)d_in[2];
  const float* W    = (const float*)d_in[3];
  const float* bW   = (const float*)d_in[4];
  const float* Ws0  = (const float*)d_in[5];
  const float* bs0  = (const float*)d_in[6];
  const float* Ws1  = (const float*)d_in[7];
  const float* bs1  = (const float*)d_in[8];
  const float* Ws01 = (const float*)d_in[9];
  const float* bs01 = (const float*)d_in[10];
  float* out = (float*)d_out;

  const size_t SLICE = (size_t)NN1 * NCOL;
  const size_t AT_B  = (size_t)1024 * 1024 * 2;      // adj0^T bf16 (ps=1 swz)
  const size_t A1T_B = (size_t)256 * 256 * 2;        // adj1^T bf16 (ps=1 swz)
  const size_t XT_B  = (size_t)NCOL * 1024 * 2;      // per-batch, 8.4 MB
  const size_t Y0_B  = SLICE * 2;                    // per-batch bf16
  const size_t HEAD  = AT_B + A1T_B;
  const size_t PER_B = XT_B + Y0_B;

  int nb_max = (int)((ws_size > HEAD ? ws_size - HEAD : 0) / PER_B);
  if (nb_max > BB) nb_max = BB;
  if (nb_max < 1)  nb_max = 1;

  ushort* At  = (ushort*)d_ws;
  ushort* A1t = (ushort*)((char*)d_ws + AT_B);
  ushort* Xt  = (ushort*)((char*)d_ws + HEAD);
  ushort* y0  = (ushort*)((char*)d_ws + HEAD + (size_t)nb_max * XT_B);

  k_prep<<<dim3(16, 16, 1), 256, 0, stream>>>(adj0, At, 1024, 1024, 0, 0, 1);
  k_prep<<<dim3(4, 4, 1), 256, 0, stream>>>(adj1, A1t, 256, 256, 0, 0, 1);

  for (int c0 = 0; c0 < BB; c0 += nb_max) {
    const int nb = (BB - c0 < nb_max) ? (BB - c0) : nb_max;
    const float* xc = x   + (size_t)c0 * SLICE;
    float*       oc = out + (size_t)c0 * SLICE;

    k_prep<<<dim3(NCOL / 64, 16, nb), 256, 0, stream>>>(
        xc, Xt, NCOL, 1024, SLICE, (size_t)NCOL * 1024, 1);

    dim3 g1(nb * 64);
    k_mode0_mfma<<<g1, 1024, 0, stream>>>(At, Xt, y0);

    dim3 g2(nb * NN1 / SLPB);
    k_pm<<<g2, 512, 0, stream>>>(xc, y0, A1t, W, bW, Ws0, bs0,
                                 Ws1, bs1, Ws01, bs01, oc);
  }
}

// Round 23
// 192.982 us; speedup vs baseline: 1.0920x; 1.0920x over previous
//
#include <hip/hip_runtime.h>

#define BB  8
#define NN1 1024
#define NN2 256
#define DD  16
#define EE  16
#define NCOL (NN2 * DD)   // 4096
#define SLPB 2            // slices per k_pm block

using bf16x8  = __attribute__((ext_vector_type(8))) short;
using f32x4   = __attribute__((ext_vector_type(4))) float;
using ushort8 = __attribute__((ext_vector_type(8))) unsigned short;

__device__ __forceinline__ ushort f2bf(float x) {
  unsigned u = __float_as_uint(x);
  unsigned r = (u + 0x7FFFu + ((u >> 16) & 1u)) >> 16;
  return (ushort)r;
}
__device__ __forceinline__ float bf2f(ushort u) {
  return __uint_as_float((unsigned)u << 16);
}
__device__ __forceinline__ unsigned pkbf(float a, float b) {
  return (unsigned)f2bf(a) | ((unsigned)f2bf(b) << 16);
}

#define GLDS16(g, l)                                                       \
  __builtin_amdgcn_global_load_lds(                                        \
      (const __attribute__((address_space(1))) void*)(g),                  \
      (__attribute__((address_space(3))) void*)(l), 16, 0, 0)

// ---------------------------------------------------------------------------
// k_prep: transpose + fp32->bf16 + swizzle.
//  ps=0: 16B-chunk XOR within 64B blocks, chunk g <- g ^ ((row>>1)&3)
//  ps=1: full 3-bit chunk XOR within 128B blocks: chunk g <- g ^ (row&7)
// src fp32 [kd(k)][nr], dst bf16 [nr][kd].
// ---------------------------------------------------------------------------
__global__ __launch_bounds__(256)
void k_prep(const float* __restrict__ src, ushort* __restrict__ dst,
            int nr, int kd, size_t srcBatch, size_t dstBatch, int ps) {
  __shared__ float tile[64][65];
  const int t = threadIdx.x;
  const int r0 = blockIdx.x * 64;
  const int k0 = blockIdx.y * 64;
  const float* s = src + (size_t)blockIdx.z * srcBatch;
  ushort* d = dst + (size_t)blockIdx.z * dstBatch;

#pragma unroll
  for (int it = 0; it < 4; ++it) {
    const int kr = it * 16 + (t >> 4);
    const int rc = (t & 15) * 4;
    float4 v = *reinterpret_cast<const float4*>(&s[(size_t)(k0 + kr) * nr + r0 + rc]);
    tile[kr][rc] = v.x; tile[kr][rc + 1] = v.y;
    tile[kr][rc + 2] = v.z; tile[kr][rc + 3] = v.w;
  }
  __syncthreads();

#pragma unroll
  for (int pass = 0; pass < 2; ++pass) {
    const int task = t + pass * 256;
    const int pr = task >> 3;
    const int gl = task & 7;
    const int r = r0 + pr;
    int klb;
    if (ps) {
      klb = (gl ^ (r & 7)) * 8;
    } else {
      const int f = (r >> 1) & 3;
      klb = (gl >> 2) * 32 + ((gl & 3) ^ f) * 8;
    }
    unsigned w[4];
#pragma unroll
    for (int e2 = 0; e2 < 4; ++e2)
      w[e2] = pkbf(tile[klb + e2 * 2][pr], tile[klb + e2 * 2 + 1][pr]);
    *reinterpret_cast<uint4*>(&d[(size_t)r * kd + k0 + gl * 8]) =
        *reinterpret_cast<const uint4*>(w);
  }
}

// ---------------------------------------------------------------------------
// k_mode0_mfma: y[b][p][c] = sum_k adj0[k][p] * X[b][k][c] -> bf16
// R15-exact (the working 8-phase): 256x256 tile, BK=64, 16 waves, acc[4][4].
// ---------------------------------------------------------------------------
__global__ __launch_bounds__(1024)
void k_mode0_mfma(const ushort* __restrict__ At, const ushort* __restrict__ Xt,
                  ushort* __restrict__ Y) {
  __shared__ ushort As[2][16384];
  __shared__ ushort Bs[2][16384];

  const int t = threadIdx.x;
  const int lane = t & 63;
  const int wid = t >> 6;
  const int wr = wid >> 2;
  const int wc = wid & 3;

  const int nwg = (int)gridDim.x;
  const int wg  = (int)blockIdx.x;
  const int orig = (wg & 7) * (nwg >> 3) + (wg >> 3);
  const int b  = orig >> 6;
  const int rem = orig & 63;
  const int c0 = (rem >> 2) << 8;
  const int p0 = (rem & 3) << 8;

  const ushort* Bb = Xt + (size_t)b * (NCOL * 1024);

  f32x4 acc[4][4];
#pragma unroll
  for (int i = 0; i < 4; ++i)
#pragma unroll
    for (int j = 0; j < 4; ++j) acc[i][j] = (f32x4)0.f;

  const int lm = lane & 15, g = lane >> 4;

  const int ksx0 = (g ^ (lm & 7)) << 3;
  const int ksx1 = ksx0 ^ 32;
  int aoff[4], boff[4];
#pragma unroll
  for (int f = 0; f < 4; ++f) {
    aoff[f] = (wr * 64 + f * 16 + lm) * 64;
    boff[f] = (wc * 64 + f * 16 + lm) * 64;
  }

#define STG_A(buf, kt, h) do {                                             \
    const int rs_ = ((wid >> 2) << 6) + (h) * 32 + ((wid & 3) << 3);       \
    GLDS16(At + (size_t)(p0 + rs_ + (lane >> 3)) * 1024 + (kt) * 64 +      \
               (lane & 7) * 8, &As[buf][rs_ * 64]);                        \
  } while (0)

#define STG_B(buf, kt, h) do {                                             \
    const int rs_ = ((wid >> 2) << 6) + (h) * 32 + ((wid & 3) << 3);       \
    GLDS16(Bb + (size_t)(c0 + rs_ + (lane >> 3)) * 1024 + (kt) * 64 +      \
               (lane & 7) * 8, &Bs[buf][rs_ * 64]);                        \
  } while (0)

#define VM3 asm volatile("s_waitcnt vmcnt(3)" ::: "memory")
#define VM2 asm volatile("s_waitcnt vmcnt(2)" ::: "memory")
#define VM1 asm volatile("s_waitcnt vmcnt(1)" ::: "memory")
#define VM0 asm volatile("s_waitcnt vmcnt(0)" ::: "memory")
#define NOWAIT ((void)0)
#define NOSTG  ((void)0)

#define PHASE(buf, qi, qj, STGSTMT, WAITSTMT) do {                         \
    STGSTMT;                                                               \
    WAITSTMT;                                                              \
    __builtin_amdgcn_s_barrier();                                          \
    __builtin_amdgcn_sched_barrier(0);                                     \
    bf16x8 a00 = *reinterpret_cast<const bf16x8*>(&As[buf][aoff[(qi)*2+0] + ksx0]); \
    bf16x8 a10 = *reinterpret_cast<const bf16x8*>(&As[buf][aoff[(qi)*2+1] + ksx0]); \
    bf16x8 b00 = *reinterpret_cast<const bf16x8*>(&Bs[buf][boff[(qj)*2+0] + ksx0]); \
    bf16x8 b10 = *reinterpret_cast<const bf16x8*>(&Bs[buf][boff[(qj)*2+1] + ksx0]); \
    bf16x8 a01 = *reinterpret_cast<const bf16x8*>(&As[buf][aoff[(qi)*2+0] + ksx1]); \
    bf16x8 a11 = *reinterpret_cast<const bf16x8*>(&As[buf][aoff[(qi)*2+1] + ksx1]); \
    bf16x8 b01 = *reinterpret_cast<const bf16x8*>(&Bs[buf][boff[(qj)*2+0] + ksx1]); \
    bf16x8 b11 = *reinterpret_cast<const bf16x8*>(&Bs[buf][boff[(qj)*2+1] + ksx1]); \
    __builtin_amdgcn_s_setprio(1);                                         \
    acc[(qi)*2+0][(qj)*2+0] = __builtin_amdgcn_mfma_f32_16x16x32_bf16(a00, b00, acc[(qi)*2+0][(qj)*2+0], 0, 0, 0); \
    acc[(qi)*2+0][(qj)*2+1] = __builtin_amdgcn_mfma_f32_16x16x32_bf16(a00, b10, acc[(qi)*2+0][(qj)*2+1], 0, 0, 0); \
    acc[(qi)*2+1][(qj)*2+0] = __builtin_amdgcn_mfma_f32_16x16x32_bf16(a10, b00, acc[(qi)*2+1][(qj)*2+0], 0, 0, 0); \
    acc[(qi)*2+1][(qj)*2+1] = __builtin_amdgcn_mfma_f32_16x16x32_bf16(a10, b10, acc[(qi)*2+1][(qj)*2+1], 0, 0, 0); \
    acc[(qi)*2+0][(qj)*2+0] = __builtin_amdgcn_mfma_f32_16x16x32_bf16(a01, b01, acc[(qi)*2+0][(qj)*2+0], 0, 0, 0); \
    acc[(qi)*2+0][(qj)*2+1] = __builtin_amdgcn_mfma_f32_16x16x32_bf16(a01, b11, acc[(qi)*2+0][(qj)*2+1], 0, 0, 0); \
    acc[(qi)*2+1][(qj)*2+0] = __builtin_amdgcn_mfma_f32_16x16x32_bf16(a11, b01, acc[(qi)*2+1][(qj)*2+0], 0, 0, 0); \
    acc[(qi)*2+1][(qj)*2+1] = __builtin_amdgcn_mfma_f32_16x16x32_bf16(a11, b11, acc[(qi)*2+1][(qj)*2+1], 0, 0, 0); \
    __builtin_amdgcn_s_setprio(0);                                         \
  } while (0)

  STG_A(0, 0, 0); STG_B(0, 0, 0); STG_A(0, 0, 1); STG_B(0, 0, 1);

  for (int it = 0; it < 8; ++it) {
    const int t1 = 2 * it + 1, t2 = 2 * it + 2;
    PHASE(0, 0, 0, STG_A(1, t1, 0), VM3);
    PHASE(0, 1, 0, STG_B(1, t1, 0), VM3);
    PHASE(0, 0, 1, STG_A(1, t1, 1), VM3);
    PHASE(0, 1, 1, STG_B(1, t1, 1), NOWAIT);
    __builtin_amdgcn_s_barrier();
    if (it < 7) {
      PHASE(1, 0, 0, STG_A(0, t2, 0), VM3);
      PHASE(1, 1, 0, STG_B(0, t2, 0), VM3);
      PHASE(1, 0, 1, STG_A(0, t2, 1), VM3);
      PHASE(1, 1, 1, STG_B(0, t2, 1), NOWAIT);
    } else {
      PHASE(1, 0, 0, NOSTG, VM2);
      PHASE(1, 1, 0, NOSTG, VM1);
      PHASE(1, 0, 1, NOSTG, VM0);
      PHASE(1, 1, 1, NOSTG, NOWAIT);
    }
    __builtin_amdgcn_s_barrier();
  }
#undef PHASE
#undef STG_A
#undef STG_B

  ushort* Yb = Y + (size_t)b * ((size_t)NN1 * NCOL);
  const int orow = g * 4;
#pragma unroll
  for (int i = 0; i < 4; ++i)
#pragma unroll
    for (int j = 0; j < 4; ++j) {
      const int p = p0 + wr * 64 + i * 16 + orow;
      const int c = c0 + wc * 64 + j * 16 + lm;
      ushort* dst = Yb + (size_t)p * NCOL + c;
#pragma unroll
      for (int e = 0; e < 4; ++e) dst[(size_t)e * NCOL] = f2bf(acc[i][j][e]);
    }
}

// ---------------------------------------------------------------------------
// k_pm: fused projection(MFMA) + mode1 per SLPB slices (512 thr).
// R16-exact (best measured): xy pitch-40 staging, proj MFMAs with r in acc,
// s -> St (mode1c Bs layout), phase-2 BK=64 double-buffered A1t (ps=1 swz),
// LDS 80 KB (As dbuf aliases xy region).
// ---------------------------------------------------------------------------
__global__ __launch_bounds__(512)
void k_pm(const float* __restrict__ x, const ushort* __restrict__ y0,
          const ushort* __restrict__ A1t,
          const float* __restrict__ W,   const float* __restrict__ bW,
          const float* __restrict__ W0,  const float* __restrict__ b0,
          const float* __restrict__ W1,  const float* __restrict__ b1,
          const float* __restrict__ W01, const float* __restrict__ b01,
          float* __restrict__ out) {
  __shared__ ushort SH[40960];       // 80 KB
  ushort* xy  = SH;                  // phase 1: 512 rows x 40 (x|y|pad)
  ushort* Asb = SH;                  // phase 2: 2 bufs x 16384 (256 q x 64 k)
  ushort* Stp = SH + 32768;          // 8 kc x 32 m x 32 j  (16 KB)

  const int t = threadIdx.x;
  const int lane = t & 63;
  const int wid = t >> 6;            // 0..7
  const int lm = lane & 15, g = lane >> 4;
  const int wq  = wid >> 1;          // 0..3 : 64-q stripe
  const int wmi = wid & 1;           // 0..1 : slice
  const size_t sl0 = (size_t)blockIdx.x * SLPB;

  // ---- phase 1a: stage x (convert) and y0 rows into xy (pitch 40) ----
  {
    const size_t base = (sl0 * NCOL) + (size_t)t * DD;   // row j_global = t
    const float4 x0 = *reinterpret_cast<const float4*>(&x[base]);
    const float4 x1 = *reinterpret_cast<const float4*>(&x[base + 4]);
    const float4 x2 = *reinterpret_cast<const float4*>(&x[base + 8]);
    const float4 x3 = *reinterpret_cast<const float4*>(&x[base + 12]);
    const uint4 yv0 = *reinterpret_cast<const uint4*>(&y0[base]);
    const uint4 yv1 = *reinterpret_cast<const uint4*>(&y0[base + 8]);
    unsigned xw0[4] = {pkbf(x0.x, x0.y), pkbf(x0.z, x0.w), pkbf(x1.x, x1.y), pkbf(x1.z, x1.w)};
    unsigned xw1[4] = {pkbf(x2.x, x2.y), pkbf(x2.z, x2.w), pkbf(x3.x, x3.y), pkbf(x3.z, x3.w)};
    ushort* row = xy + t * 40;
    *reinterpret_cast<uint4*>(row)      = *reinterpret_cast<const uint4*>(xw0);
    *reinterpret_cast<uint4*>(row + 8)  = *reinterpret_cast<const uint4*>(xw1);
    *reinterpret_cast<uint4*>(row + 16) = yv0;
    *reinterpret_cast<uint4*>(row + 24) = yv1;
  }

  // ---- W fragments + bias (k = g*8+jj over [x(16)|y0(16)]) ----
  bf16x8 wfr, wfs;
#pragma unroll
  for (int jj = 0; jj < 8; ++jj) {
    const int k = g * 8 + jj;
    const float vr = (k < 16) ? W[k * 16 + lm]  : W0[(k - 16) * 16 + lm];
    const float vs = (k < 16) ? W1[k * 16 + lm] : W01[(k - 16) * 16 + lm];
    wfr[jj] = (short)f2bf(vr);
    wfs[jj] = (short)f2bf(vs);
  }
  const float bias = bW[lm] + b0[lm] + b1[lm] + b01[lm];

  __syncthreads();

  // ---- phase 1b: projection MFMAs; r accumulates in acc, s -> St ----
  f32x4 acc[4];
#pragma unroll
  for (int i = 0; i < 4; ++i) {
    const int grp = wmi * 16 + wq * 4 + i;
    const int row = grp * 16 + lm;
    const bf16x8 a = *reinterpret_cast<const bf16x8*>(&xy[row * 40 + g * 8]);

    f32x4 cb; cb[0] = bias; cb[1] = bias; cb[2] = bias; cb[3] = bias;
    acc[i] = __builtin_amdgcn_mfma_f32_16x16x32_bf16(a, wfr, cb, 0, 0, 0);
    const f32x4 sD = __builtin_amdgcn_mfma_f32_16x16x32_bf16(a, wfs, (f32x4)0.f, 0, 0, 0);

    const int m = wmi * 16 + lm;
    const int kc = wq * 2 + (i >> 1);
    const int chunkL = ((i & 1) << 1) + (g >> 1);
    const int phys = chunkL ^ ((m >> 1) & 3);
    unsigned pw[2] = {pkbf(sD[0], sD[1]), pkbf(sD[2], sD[3])};
    *reinterpret_cast<uint2*>(&Stp[kc * 1024 + m * 32 + phys * 8 + (g & 1) * 4]) =
        *reinterpret_cast<const uint2*>(pw);
  }

  __syncthreads();   // St complete; all xy reads done -> Asb region free

  // ---- phase 2: mode1 GEMM, BK=64 (4 iters x 8 MFMAs) ----
#define STAGEA(buf, kt)                                                    \
  do {                                                                     \
    _Pragma("unroll")                                                      \
    for (int is = 0; is < 4; ++is) {                                       \
      const int rowbase = wid * 32 + is * 8;                               \
      GLDS16(A1t + (size_t)(rowbase + (lane >> 3)) * 256 + (kt) * 64 +     \
                 (lane & 7) * 8,                                           \
             Asb + (buf) * 16384 + rowbase * 64);                          \
    }                                                                      \
  } while (0)

  int aro[4][2];
#pragma unroll
  for (int f = 0; f < 4; ++f) {
    const int ra = wq * 64 + f * 16 + lm;
#pragma unroll
    for (int ks = 0; ks < 2; ++ks)
      aro[f][ks] = ra * 64 + (((ks * 4 + g) ^ (ra & 7)) << 3);
  }
  const int rwB = wmi * 16 + lm;
  const int bofs = (rwB * 32) + ((g ^ ((rwB >> 1) & 3)) << 3);

  STAGEA(0, 0);
  int cur = 0;
  for (int kt = 0; kt < 4; ++kt) {
    if (kt < 3) {
      STAGEA(cur ^ 1, kt + 1);
      asm volatile("s_waitcnt vmcnt(4)" ::: "memory");
    } else {
      asm volatile("s_waitcnt vmcnt(0)" ::: "memory");
    }
    __builtin_amdgcn_s_barrier();
    __builtin_amdgcn_sched_barrier(0);

#pragma unroll
    for (int ks = 0; ks < 2; ++ks) {
      const int kc = kt * 2 + ks;
      bf16x8 af[4];
#pragma unroll
      for (int f = 0; f < 4; ++f)
        af[f] = *reinterpret_cast<const bf16x8*>(&Asb[cur * 16384 + aro[f][ks]]);
      const bf16x8 bfr = *reinterpret_cast<const bf16x8*>(&Stp[kc * 1024 + bofs]);
      __builtin_amdgcn_s_setprio(1);
#pragma unroll
      for (int i = 0; i < 4; ++i)
        acc[i] = __builtin_amdgcn_mfma_f32_16x16x32_bf16(af[i], bfr, acc[i], 0, 0, 0);
      __builtin_amdgcn_s_setprio(0);
    }

    __builtin_amdgcn_sched_barrier(0);
    __builtin_amdgcn_s_barrier();
    cur ^= 1;
  }
#undef STAGEA

  // ---- epilogue: out = relu(acc), single fp32 write ----
  float* os = out + (sl0 + wmi) * NCOL;
#pragma unroll
  for (int i = 0; i < 4; ++i) {
    const int qb = wq * 64 + i * 16 + g * 4;
#pragma unroll
    for (int rr = 0; rr < 4; ++rr)
      os[(size_t)(qb + rr) * EE + lm] = fmaxf(acc[i][rr], 0.f);
  }
}

// ---------------------------------------------------------------------------
extern "C" void kernel_launch(void* const* d_in, const int* in_sizes, int n_in,
                              void* d_out, int out_size, void* d_ws, size_t ws_size,
                              hipStream_t stream) {
  const float* x    = (const float*)d_in[0];
  const float* adj0 = (const float*)d_in[1];
  const float* adj1 = (const float*)d_in[2];
  const float* W    = (const float*)d_in[3];
  const float* bW   = (const float*)d_in[4];
  const float* Ws0  = (const float*)d_in[5];
  const float* bs0  = (const float*)d_in[6];
  const float* Ws1  = (const float*)d_in[7];
  const float* bs1  = (const float*)d_in[8];
  const float* Ws01 = (const float*)d_in[9];
  const float* bs01 = (const float*)d_in[10];
  float* out = (float*)d_out;

  const size_t SLICE = (size_t)NN1 * NCOL;
  const size_t AT_B  = (size_t)1024 * 1024 * 2;      // adj0^T bf16 (ps=1 swz)
  const size_t A1T_B = (size_t)256 * 256 * 2;        // adj1^T bf16 (ps=1 swz)
  const size_t XT_B  = (size_t)NCOL * 1024 * 2;      // per-batch, 8.4 MB
  const size_t Y0_B  = SLICE * 2;                    // per-batch bf16
  const size_t HEAD  = AT_B + A1T_B;
  const size_t PER_B = XT_B + Y0_B;

  int nb_max = (int)((ws_size > HEAD ? ws_size - HEAD : 0) / PER_B);
  if (nb_max > BB) nb_max = BB;
  if (nb_max < 1)  nb_max = 1;

  ushort* At  = (ushort*)d_ws;
  ushort* A1t = (ushort*)((char*)d_ws + AT_B);
  ushort* Xt  = (ushort*)((char*)d_ws + HEAD);
  ushort* y0  = (ushort*)((char*)d_ws + HEAD + (size_t)nb_max * XT_B);

  k_prep<<<dim3(16, 16, 1), 256, 0, stream>>>(adj0, At, 1024, 1024, 0, 0, 1);
  k_prep<<<dim3(4, 4, 1), 256, 0, stream>>>(adj1, A1t, 256, 256, 0, 0, 1);

  for (int c0 = 0; c0 < BB; c0 += nb_max) {
    const int nb = (BB - c0 < nb_max) ? (BB - c0) : nb_max;
    const float* xc = x   + (size_t)c0 * SLICE;
    float*       oc = out + (size_t)c0 * SLICE;

    k_prep<<<dim3(NCOL / 64, 16, nb), 256, 0, stream>>>(
        xc, Xt, NCOL, 1024, SLICE, (size_t)NCOL * 1024, 1);

    dim3 g1(nb * 64);
    k_mode0_mfma<<<g1, 1024, 0, stream>>>(At, Xt, y0);

    dim3 g2(nb * NN1 / SLPB);
    k_pm<<<g2, 512, 0, stream>>>(xc, y0, A1t, W, bW, Ws0, bs0,
                                 Ws1, bs1, Ws01, bs01, oc);
  }
}